// Round 8
// baseline (110.670 us; speedup 1.0000x reference)
//
#include <hip/hip_runtime.h>

// IndRNN only-recurrent: h_t = relu(x_t + w * h_{t-1}), elementwise over [B,H],
// sequential over T. Pure HBM-streaming: 256 MiB in + 256 MiB out.
//
// R8: identical to R6/R7 (both infra failures, never ran). Non-temporal
// loads+stores on the two 256 MB zero-reuse streams via native
// ext_vector_type(4) (required by __builtin_nontemporal_*; HIP_vector_type is
// rejected). Config is the R1 winner (VEC=4, DEPTH=16, 256x64, 1 wave/CU,
// 95.4 us baseline).

typedef float f32x4 __attribute__((ext_vector_type(4)));

constexpr int T     = 1024;
constexpr int B     = 64;
constexpr int H     = 1024;
constexpr int N     = B * H;        // 65536 elements per timestep
constexpr int VEC   = 4;
constexpr int NT    = N / VEC;      // 16384 float4's per timestep
constexpr int BLOCK = 64;
constexpr int GRID  = NT / BLOCK;   // 256 blocks -> 1 per CU
constexpr int DEPTH = 16;           // 64 lanes x 16 x 16B = 16 KiB/CU in flight

__global__ __launch_bounds__(BLOCK) void indrnn_kernel(
    const f32x4* __restrict__ x,    // [T][NT] as f32x4
    const f32x4* __restrict__ h0,   // [NT]
    const float* __restrict__ w,    // [H]
    f32x4*       __restrict__ out)  // [T][NT]
{
    const int tid = blockIdx.x * BLOCK + threadIdx.x;   // 0..NT-1
    const int e   = tid * VEC;                          // first element index

    // All 4 elements share the same batch row; weight index (e % H), 16B-aligned.
    const f32x4 wv = *reinterpret_cast<const f32x4*>(w + (e & (H - 1)));
    f32x4 h = h0[tid];

    const f32x4* xp = x + tid;
    f32x4*       op = out + tid;

    // Prefetch pipeline: buf[i] holds x_{t+i}. All indices compile-time
    // constants after unroll (registers, not scratch — rule #20).
    f32x4 buf[DEPTH];
#pragma unroll
    for (int i = 0; i < DEPTH; ++i) buf[i] = __builtin_nontemporal_load(xp + i * NT);

    int t = 0;
    for (; t < T - DEPTH; t += DEPTH) {
#pragma unroll
        for (int i = 0; i < DEPTH; ++i) {
            const f32x4 xv = buf[i];
            buf[i] = __builtin_nontemporal_load(xp + (t + DEPTH + i) * NT);
            h.x = fmaxf(fmaf(h.x, wv.x, xv.x), 0.0f);
            h.y = fmaxf(fmaf(h.y, wv.y, xv.y), 0.0f);
            h.z = fmaxf(fmaf(h.z, wv.z, xv.z), 0.0f);
            h.w = fmaxf(fmaf(h.w, wv.w, xv.w), 0.0f);
            __builtin_nontemporal_store(h, op + (t + i) * NT);
        }
    }
    // Tail: last DEPTH timesteps, no prefetch.
#pragma unroll
    for (int i = 0; i < DEPTH; ++i) {
        const f32x4 xv = buf[i];
        h.x = fmaxf(fmaf(h.x, wv.x, xv.x), 0.0f);
        h.y = fmaxf(fmaf(h.y, wv.y, xv.y), 0.0f);
        h.z = fmaxf(fmaf(h.z, wv.z, xv.z), 0.0f);
        h.w = fmaxf(fmaf(h.w, wv.w, xv.w), 0.0f);
        __builtin_nontemporal_store(h, op + (t + i) * NT);
    }
}

extern "C" void kernel_launch(void* const* d_in, const int* in_sizes, int n_in,
                              void* d_out, int out_size, void* d_ws, size_t ws_size,
                              hipStream_t stream) {
    const f32x4* x  = (const f32x4*)d_in[0];  // input  [T,B,H] fp32
    const f32x4* h0 = (const f32x4*)d_in[1];  // h0     [B,H]   fp32
    const float* w  = (const float*)d_in[2];  // weight [H]     fp32
    f32x4* out = (f32x4*)d_out;               // output [T,B,H] fp32

    indrnn_kernel<<<GRID, BLOCK, 0, stream>>>(x, h0, w, out);
}

// Round 9
// 96.103 us; speedup vs baseline: 1.1516x; 1.1516x over previous
//
#include <hip/hip_runtime.h>

// IndRNN only-recurrent: h_t = relu(x_t + w * h_{t-1}), elementwise over [B,H],
// sequential over T. Pure HBM-streaming: 256 MiB in + 256 MiB out.
//
// R9: REVERT to the R1 winner (95.4 us = 5.63 TB/s, 89.5% of the 6.29 TB/s
// measured copy ceiling). Ablation history:
//   R3  2 waves/CU (VEC=2, BLOCK=128)  -> neutral (96.8)
//   R4  DEPTH=32 (32 KiB/CU in flight) -> hurt   (101.6)
//   R8  non-temporal loads+stores      -> hurt   (110.7)
// Config: VEC=4 (16B/lane), DEPTH=16 prefetch (16 KiB/CU in flight),
// 256 blocks x 64 threads = 1 wave/CU. Serial h-chain lives in registers;
// load addresses are h-independent so they pipeline DEPTH steps ahead.

constexpr int T     = 1024;
constexpr int B     = 64;
constexpr int H     = 1024;
constexpr int N     = B * H;        // 65536 elements per timestep
constexpr int VEC   = 4;
constexpr int NT    = N / VEC;      // 16384 float4's per timestep
constexpr int BLOCK = 64;
constexpr int GRID  = NT / BLOCK;   // 256 blocks -> 1 per CU
constexpr int DEPTH = 16;           // 64 lanes x 16 x 16B = 16 KiB/CU in flight

__global__ __launch_bounds__(BLOCK) void indrnn_kernel(
    const float4* __restrict__ x,    // [T][NT] as float4
    const float4* __restrict__ h0,   // [NT]
    const float*  __restrict__ w,    // [H]
    float4*       __restrict__ out)  // [T][NT]
{
    const int tid = blockIdx.x * BLOCK + threadIdx.x;   // 0..NT-1
    const int e   = tid * VEC;                          // first element index

    // All 4 elements share the same batch row; weight index (e % H), 16B-aligned.
    const float4 wv = *reinterpret_cast<const float4*>(w + (e & (H - 1)));
    float4 h = h0[tid];

    const float4* xp = x + tid;
    float4*       op = out + tid;

    // Prefetch pipeline: buf[i] holds x_{t+i}. All indices compile-time
    // constants after unroll (registers, not scratch — rule #20).
    float4 buf[DEPTH];
#pragma unroll
    for (int i = 0; i < DEPTH; ++i) buf[i] = xp[i * NT];

    int t = 0;
    for (; t < T - DEPTH; t += DEPTH) {
#pragma unroll
        for (int i = 0; i < DEPTH; ++i) {
            const float4 xv = buf[i];
            buf[i] = xp[(t + DEPTH + i) * NT];   // issue next load early
            h.x = fmaxf(fmaf(h.x, wv.x, xv.x), 0.0f);
            h.y = fmaxf(fmaf(h.y, wv.y, xv.y), 0.0f);
            h.z = fmaxf(fmaf(h.z, wv.z, xv.z), 0.0f);
            h.w = fmaxf(fmaf(h.w, wv.w, xv.w), 0.0f);
            op[(t + i) * NT] = h;
        }
    }
    // Tail: last DEPTH timesteps, no prefetch.
#pragma unroll
    for (int i = 0; i < DEPTH; ++i) {
        const float4 xv = buf[i];
        h.x = fmaxf(fmaf(h.x, wv.x, xv.x), 0.0f);
        h.y = fmaxf(fmaf(h.y, wv.y, xv.y), 0.0f);
        h.z = fmaxf(fmaf(h.z, wv.z, xv.z), 0.0f);
        h.w = fmaxf(fmaf(h.w, wv.w, xv.w), 0.0f);
        op[(t + i) * NT] = h;
    }
}

extern "C" void kernel_launch(void* const* d_in, const int* in_sizes, int n_in,
                              void* d_out, int out_size, void* d_ws, size_t ws_size,
                              hipStream_t stream) {
    const float4* x  = (const float4*)d_in[0];  // input  [T,B,H] fp32
    const float4* h0 = (const float4*)d_in[1];  // h0     [B,H]   fp32
    const float*  w  = (const float*)d_in[2];   // weight [H]     fp32
    float4* out = (float4*)d_out;               // output [T,B,H] fp32

    indrnn_kernel<<<GRID, BLOCK, 0, stream>>>(x, h0, w, out);
}